// Round 1
// 3938.661 us; speedup vs baseline: 1.8229x; 1.8229x over previous
//
#include <hip/hip_runtime.h>
#include <stdint.h>

#define BATCH 256
#define SEQ   365
#define HID   256
#define INSZ  32
#define NGATE 1024
#define KTOT  288            // INSZ + HID
#define NKC   9              // K chunks of 32
#define AS    296            // shorts per A row (XOR-swizzled 16B blocks)
#define WTOT  (KTOT*NGATE)   // 294912 elements per weight array

#define NSPLIT 4             // blocks per batch group (gate-column split)
#define NGRP   16            // batch groups of 16 rows
#define NBLK   (NGRP*NSPLIT) // 64 blocks
#define HSLICE 64            // hidden cols per block

// workspace layout (bytes)
#define FLAG_OFF (2*WTOT*2)          // 1,179,648 : after wsw hi+lo
#define HX_OFF   (FLAG_OFF + 256)    // hx: NGRP * 2(bufs) * 16*256 u32 = 512 KB

typedef __bf16 bf16x8 __attribute__((ext_vector_type(8)));
typedef short  s16x8  __attribute__((ext_vector_type(8)));
typedef short  s16x4  __attribute__((ext_vector_type(4)));
typedef float  f32x4  __attribute__((ext_vector_type(4)));
typedef unsigned int u32x4 __attribute__((ext_vector_type(4)));

__device__ __forceinline__ unsigned short f2bf(float f) {
    unsigned u = __float_as_uint(f);
    u += 0x7FFFu + ((u >> 16) & 1u);          // round-to-nearest-even
    return (unsigned short)(u >> 16);
}
__device__ __forceinline__ float bf2f(unsigned short h) {
    return __uint_as_float(((unsigned)h) << 16);
}
__device__ __forceinline__ float sigm(float x) { return 1.f / (1.f + __expf(-x)); }
__device__ __forceinline__ float tanh_f(float x) {
    float e = __expf(-2.f * fabsf(x));
    float r = (1.f - e) / (1.f + e);
    return copysignf(r, x);
}

// One-time: W^T (w_ih stacked over w_hh) -> bf16 hi/lo in MFMA-B-fragment order.
// Also zeroes the sync flags (re-runs every launch -> graph-replay safe).
__global__ void swizzle_w(const float* __restrict__ w_ih,
                          const float* __restrict__ w_hh,
                          unsigned short* __restrict__ wsw,
                          unsigned int* __restrict__ flags)
{
    if (blockIdx.x == 0 && threadIdx.x < NBLK) flags[threadIdx.x] = 0u;
    int idx = blockIdx.x*256 + threadIdx.x;      // idx = k*1024 + n
    int k = idx >> 10, n = idx & 1023;
    float v = (k < INSZ) ? w_ih[k*NGATE + n] : w_hh[(k-INSZ)*NGATE + n];
    unsigned short hi = f2bf(v);
    unsigned short lo = f2bf(v - bf2f(hi));
    int t = n >> 4, l15 = n & 15, c = k >> 5, q = (k >> 3) & 3, j = k & 7;
    int off = ((t*NKC + c)*64 + q*16 + l15)*8 + j;
    wsw[off]        = hi;
    wsw[WTOT + off] = lo;
}

// Physical LDS address for A element (row r, logical k): 16B blocks XOR-swizzled by r&3.
__device__ __forceinline__ int a_addr(int r, int k) {
    return r*AS + ((((k >> 3) ^ (r & 3))) << 3) + (k & 7);
}

__global__ __launch_bounds__(256, 1) void lstm_seq(
    const float* __restrict__ x,      // [B][SEQ][INSZ]
    const unsigned short* __restrict__ wsw,
    const float* __restrict__ bias,   // [NGATE]
    const float* __restrict__ fc_w,   // [HID]
    const float* __restrict__ fc_b,   // [1]
    float* __restrict__ out,          // [B]
    float* __restrict__ h_n,          // [B][SEQ][HID]
    float* __restrict__ c_n,          // [B][SEQ][HID]
    unsigned int* __restrict__ flags, // [NBLK]
    unsigned int* __restrict__ hx)    // [NGRP][2][16][HID] packed (hi<<16)|lo
{
    __shared__ short a_hi[16*AS];     // A = [x_t | h] hi, XOR-swizzled blocks
    __shared__ short a_lo[16*AS];
    __shared__ float red[16*17];      // FC reduction

    const int tid  = threadIdx.x;
    const int gq   = blockIdx.x >> 2;       // batch group
    const int sl   = blockIdx.x & 3;        // gate-column slice
    const int b0   = gq * 16;
    const int wv   = tid >> 6, lane = tid & 63;
    const int l15  = lane & 15, q = lane >> 4;
    const int hcol = sl*HSLICE + wv*16 + l15;   // this thread's hidden column

    unsigned int* const hxg = hx + (size_t)gq * 2 * (16*HID);
    unsigned int* const flg = flags + gq*NSPLIT;

    float bia[4];
    #pragma unroll
    for (int G = 0; G < 4; ++G) bia[G] = bias[G*HID + hcol];

    float cst[4];                     // c state: row = q*4+i, col = hcol
    #pragma unroll
    for (int i = 0; i < 4; ++i) cst[i] = 0.f;

    // ---- initial staging: zero all of A, then x(s=0) ----
    for (int i = tid; i < 16*AS; i += 256) { a_hi[i] = 0; a_lo[i] = 0; }
    __syncthreads();
    {
        int r = tid >> 5, k = tid & 31;       // rows 0..7 and 8..15
        float v0 = x[((size_t)(b0 + r)*SEQ + 0)*INSZ + k];
        float v1 = x[((size_t)(b0 + 8 + r)*SEQ + 0)*INSZ + k];
        unsigned short h0 = f2bf(v0);
        int pa0 = a_addr(r, k);
        a_hi[pa0] = (short)h0; a_lo[pa0] = (short)f2bf(v0 - bf2f(h0));
        unsigned short h1 = f2bf(v1);
        int pa1 = a_addr(r + 8, k);
        a_hi[pa1] = (short)h1; a_lo[pa1] = (short)f2bf(v1 - bf2f(h1));
    }

    for (int s = 0; s < SEQ; ++s) {
        __syncthreads();              // A(s) ready

        // prefetch x(s+1) early (hides under the MFMA/W stream)
        float xv0 = 0.f, xv1 = 0.f;
        if (s + 1 < SEQ) {
            int r = tid >> 5, k = tid & 31;
            xv0 = x[((size_t)(b0 + r)*SEQ + (s+1))*INSZ + k];
            xv1 = x[((size_t)(b0 + 8 + r)*SEQ + (s+1))*INSZ + k];
        }

        // ---- MFMA phase: A[16x288] (LDS) x W-slice frags streamed from L2 ----
        f32x4 acc[4];
        #pragma unroll
        for (int G = 0; G < 4; ++G) acc[G] = (f32x4){0.f,0.f,0.f,0.f};

        const int qs = (q ^ (l15 & 3)) << 3;
        #pragma unroll 3
        for (int c = 0; c < NKC; ++c) {
            int pk = l15*AS + c*32 + qs;
            bf16x8 ah = __builtin_bit_cast(bf16x8, *(const s16x8*)&a_hi[pk]);
            bf16x8 al = __builtin_bit_cast(bf16x8, *(const s16x8*)&a_lo[pk]);
            #pragma unroll
            for (int G = 0; G < 4; ++G) {
                int tile = G*16 + sl*4 + wv;
                const unsigned short* wp = wsw + ((size_t)(tile*NKC + c)*64 + lane)*8;
                bf16x8 bh = __builtin_bit_cast(bf16x8, *(const s16x8*)wp);
                bf16x8 bl = __builtin_bit_cast(bf16x8, *(const s16x8*)(wp + WTOT));
                acc[G] = __builtin_amdgcn_mfma_f32_16x16x32_bf16(ah, bh, acc[G], 0,0,0);
                acc[G] = __builtin_amdgcn_mfma_f32_16x16x32_bf16(ah, bl, acc[G], 0,0,0);
                acc[G] = __builtin_amdgcn_mfma_f32_16x16x32_bf16(al, bh, acc[G], 0,0,0);
            }
        }

        // ---- epilogue: activations, publish h slice (coherent), outputs ----
        unsigned int* hxw = hxg + (s & 1)*(16*HID);
        #pragma unroll
        for (int i = 0; i < 4; ++i) {
            float f  = acc[0][i] + bia[0];
            float ii = acc[1][i] + bia[1];
            float o  = acc[2][i] + bia[2];
            float gg = acc[3][i] + bia[3];
            float cn = sigm(f)*cst[i] + sigm(ii)*tanh_f(gg);
            float hn = sigm(o)*tanh_f(cn);
            cst[i] = cn;
            unsigned short hi = f2bf(hn);
            unsigned short lo = f2bf(hn - bf2f(hi));
            unsigned int pk = ((unsigned int)hi << 16) | (unsigned int)lo;
            int row = q*4 + i;
            unsigned int* hp = hxw + row*HID + hcol;
            asm volatile("global_store_dword %0, %1, off sc0 sc1"
                         :: "v"(hp), "v"(pk) : "memory");
            size_t oi = ((size_t)(b0 + row)*SEQ + s)*HID + hcol;
            h_n[oi] = hn;
            c_n[oi] = cn;
        }

        asm volatile("s_waitcnt vmcnt(0)" ::: "memory");  // publishes at coherent point
        __syncthreads();              // whole block drained + done reading A

        if (tid == 0) {               // announce slice s complete
            unsigned int fv = (unsigned int)(s + 1);
            asm volatile("global_store_dword %0, %1, off sc0 sc1"
                         :: "v"(flg + sl), "v"(fv) : "memory");
        }
        if (s + 1 == SEQ && sl != 0) return;   // block-uniform exit; slice 0 does FC

        // ---- spin for siblings (one lane), then rebuild A(s+1) ----
        if (tid == 0) {
            unsigned int tgt = (unsigned int)(s + 1);
            while (1) {
                u32x4 fv;
                asm volatile("global_load_dwordx4 %0, %1, off sc0 sc1\n\t"
                             "s_waitcnt vmcnt(0)"
                             : "=v"(fv) : "v"(flg) : "memory");
                if (fv.x >= tgt && fv.y >= tgt && fv.z >= tgt && fv.w >= tgt) break;
            }
        }
        __syncthreads();

        // h-region: 16 rows x 256 cols packed u32, 4 coherent dwordx4 loads/thread
        const unsigned int* hxr = hxg + (s & 1)*(16*HID);
        u32x4 hv4[4];
        #pragma unroll
        for (int e = 0; e < 4; ++e) {
            const unsigned int* ap = hxr + ((size_t)(e*256 + tid))*4;
            asm volatile("global_load_dwordx4 %0, %1, off sc0 sc1"
                         : "=v"(hv4[e]) : "v"(ap) : "memory");
        }
        asm volatile("s_waitcnt vmcnt(0)" ::: "memory");
        __builtin_amdgcn_sched_barrier(0);
        #pragma unroll
        for (int e = 0; e < 4; ++e) {
            int m = e*256 + tid;
            int row = m >> 6;
            int col = 4*(m & 63);
            int pa = a_addr(row, INSZ + col);   // 4 consecutive shorts, 8B-aligned
            s16x4 hi4 = (s16x4){ (short)(hv4[e].x >> 16), (short)(hv4[e].y >> 16),
                                 (short)(hv4[e].z >> 16), (short)(hv4[e].w >> 16) };
            s16x4 lo4 = (s16x4){ (short)(hv4[e].x & 0xffffu), (short)(hv4[e].y & 0xffffu),
                                 (short)(hv4[e].z & 0xffffu), (short)(hv4[e].w & 0xffffu) };
            *(s16x4*)&a_hi[pa] = hi4;
            *(s16x4*)&a_lo[pa] = lo4;
        }
        // x-region from prefetched regs
        if (s + 1 < SEQ) {
            int r = tid >> 5, k = tid & 31;
            unsigned short h0 = f2bf(xv0);
            int pa0 = a_addr(r, k);
            a_hi[pa0] = (short)h0; a_lo[pa0] = (short)f2bf(xv0 - bf2f(h0));
            unsigned short h1 = f2bf(xv1);
            int pa1 = a_addr(r + 8, k);
            a_hi[pa1] = (short)h1; a_lo[pa1] = (short)f2bf(xv1 - bf2f(h1));
        }
    }

    // ---- final FC (slice 0 only): A h-region holds h(SEQ-1) hi/lo ----
    __syncthreads();
    {
        int r = tid >> 4, seg = tid & 15;
        float acc = 0.f;
        #pragma unroll
        for (int d = 0; d < 16; ++d) {
            int j = seg*16 + d;
            int pa = a_addr(r, INSZ + j);
            acc += (bf2f((unsigned short)a_hi[pa]) + bf2f((unsigned short)a_lo[pa])) * fc_w[j];
        }
        red[r*17 + seg] = acc;
    }
    __syncthreads();
    if (tid < 16) {
        float accv = fc_b[0];
        #pragma unroll
        for (int p = 0; p < 16; ++p) accv += red[tid*17 + p];
        out[b0 + tid] = accv;
    }
}

extern "C" void kernel_launch(void* const* d_in, const int* in_sizes, int n_in,
                              void* d_out, int out_size, void* d_ws, size_t ws_size,
                              hipStream_t stream) {
    const float* x    = (const float*)d_in[0];
    const float* w_ih = (const float*)d_in[1];
    const float* w_hh = (const float*)d_in[2];
    const float* bias = (const float*)d_in[3];
    const float* fc_w = (const float*)d_in[4];
    const float* fc_b = (const float*)d_in[5];

    float* out = (float*)d_out;
    float* h_n = out + BATCH;
    float* c_n = h_n + (size_t)BATCH*SEQ*HID;

    unsigned short* wsw   = (unsigned short*)d_ws;                       // 1.125 MB
    unsigned int*   flags = (unsigned int*)((char*)d_ws + FLAG_OFF);     // 256 B
    unsigned int*   hx    = (unsigned int*)((char*)d_ws + HX_OFF);       // 512 KB

    swizzle_w<<<1152, 256, 0, stream>>>(w_ih, w_hh, wsw, flags);
    lstm_seq<<<NBLK, 256, 0, stream>>>(x, wsw, bias, fc_w, fc_b, out, h_n, c_n, flags, hx);
}

// Round 2
// 1629.831 us; speedup vs baseline: 4.4053x; 2.4166x over previous
//
#include <hip/hip_runtime.h>
#include <stdint.h>

#define BATCH 256
#define SEQ   365
#define HID   256
#define INSZ  32
#define NGATE 1024
#define KTOT  288            // INSZ + HID
#define NKC   9              // K chunks of 32
#define AS    296            // shorts per A row (XOR-swizzled 16B blocks)
#define WTOT  (KTOT*NGATE)   // 294912 elements per weight array

#define NSPLIT 4             // blocks per batch group (gate-column split)
#define NGRP   16            // batch groups of 16 rows
#define NBLK   (NGRP*NSPLIT) // 64 blocks
#define HSLICE 64            // hidden cols per block

// workspace layout (bytes)
#define FLAG_OFF (2*WTOT*2)          // 1,179,648 : after wsw hi+lo
#define HX_OFF   (FLAG_OFF + 1024)   // hx: NGRP * 2(bufs) * 16*256 u32 = 512 KB

typedef __bf16 bf16x8 __attribute__((ext_vector_type(8)));
typedef short  s16x8  __attribute__((ext_vector_type(8)));
typedef short  s16x4  __attribute__((ext_vector_type(4)));
typedef float  f32x4  __attribute__((ext_vector_type(4)));
typedef unsigned int u32x4 __attribute__((ext_vector_type(4)));

__device__ __forceinline__ unsigned short f2bf(float f) {
    unsigned u = __float_as_uint(f);
    u += 0x7FFFu + ((u >> 16) & 1u);          // round-to-nearest-even
    return (unsigned short)(u >> 16);
}
__device__ __forceinline__ float bf2f(unsigned short h) {
    return __uint_as_float(((unsigned)h) << 16);
}
__device__ __forceinline__ float sigm(float x) { return 1.f / (1.f + __expf(-x)); }
__device__ __forceinline__ float tanh_f(float x) {
    float e = __expf(-2.f * fabsf(x));
    float r = (1.f - e) / (1.f + e);
    return copysignf(r, x);
}

// One-time: W^T (w_ih stacked over w_hh) -> bf16 hi/lo in MFMA-B-fragment order.
// Also zeroes the per-wave sync flags (re-runs every launch -> graph-replay safe).
__global__ void swizzle_w(const float* __restrict__ w_ih,
                          const float* __restrict__ w_hh,
                          unsigned short* __restrict__ wsw,
                          unsigned int* __restrict__ flags)
{
    if (blockIdx.x == 0) flags[threadIdx.x] = 0u;   // 256 wave-flags
    int idx = blockIdx.x*256 + threadIdx.x;      // idx = k*1024 + n
    int k = idx >> 10, n = idx & 1023;
    float v = (k < INSZ) ? w_ih[k*NGATE + n] : w_hh[(k-INSZ)*NGATE + n];
    unsigned short hi = f2bf(v);
    unsigned short lo = f2bf(v - bf2f(hi));
    int t = n >> 4, l15 = n & 15, c = k >> 5, q = (k >> 3) & 3, j = k & 7;
    int off = ((t*NKC + c)*64 + q*16 + l15)*8 + j;
    wsw[off]        = hi;
    wsw[WTOT + off] = lo;
}

// Physical LDS address for A element (row r, logical k): 16B blocks XOR-swizzled by r&3.
__device__ __forceinline__ int a_addr(int r, int k) {
    return r*AS + ((((k >> 3) ^ (r & 3))) << 3) + (k & 7);
}

__global__ __launch_bounds__(256, 1) void lstm_seq(
    const float* __restrict__ x,      // [B][SEQ][INSZ]
    const unsigned short* __restrict__ wsw,
    const float* __restrict__ bias,   // [NGATE]
    const float* __restrict__ fc_w,   // [HID]
    const float* __restrict__ fc_b,   // [1]
    float* __restrict__ out,          // [B]
    float* __restrict__ h_n,          // [B][SEQ][HID]
    float* __restrict__ c_n,          // [B][SEQ][HID]
    unsigned int* __restrict__ flags, // [NGRP][4 slices][4 waves]
    unsigned int* __restrict__ hx)    // [NGRP][2][16][HID] packed (hi<<16)|lo
{
    __shared__ short a_hi[16*AS];     // A = [x_t | h] hi, XOR-swizzled blocks
    __shared__ short a_lo[16*AS];
    __shared__ float red[16*17];      // FC reduction

    const int tid  = threadIdx.x;
    const int gq   = blockIdx.x >> 2;       // batch group
    const int sl   = blockIdx.x & 3;        // gate-column slice
    const int b0   = gq * 16;
    const int wv   = tid >> 6, lane = tid & 63;
    const int l15  = lane & 15, q = lane >> 4;
    const int hcol = sl*HSLICE + wv*16 + l15;   // this thread's hidden column

    unsigned int* const hxg = hx + (size_t)gq * 2 * (16*HID);
    unsigned int* const flg = flags + gq*16;

    // ---- one-time: this block's W slice -> registers (72 frag pairs, 288 VGPRs) ----
    // frag (c,G) hi: wsw[((tile*NKC + c)*64 + lane)*8], tile = G*16 + sl*4 + wv
    const unsigned short* wbase = wsw + ((size_t)((sl*4 + wv)*NKC)*64 + lane)*8;
    bf16x8 wh[NKC][4], wl[NKC][4];
    #pragma unroll
    for (int c = 0; c < NKC; ++c)
        #pragma unroll
        for (int G = 0; G < 4; ++G) {
            const unsigned short* wp = wbase + (size_t)(G*16*NKC + c)*512;
            wh[c][G] = __builtin_bit_cast(bf16x8, *(const s16x8*)wp);
            wl[c][G] = __builtin_bit_cast(bf16x8, *(const s16x8*)(wp + WTOT));
        }

    float bia[4];
    #pragma unroll
    for (int G = 0; G < 4; ++G) bia[G] = bias[G*HID + hcol];

    float cst[4];                     // c state: row = q*4+i, col = hcol
    #pragma unroll
    for (int i = 0; i < 4; ++i) cst[i] = 0.f;

    // ---- initial staging: zero all of A, then x(s=0) ----
    for (int i = tid; i < 16*AS; i += 256) { a_hi[i] = 0; a_lo[i] = 0; }
    __syncthreads();
    {
        int r = tid >> 5, k = tid & 31;       // rows 0..7 and 8..15
        float v0 = x[((size_t)(b0 + r)*SEQ + 0)*INSZ + k];
        float v1 = x[((size_t)(b0 + 8 + r)*SEQ + 0)*INSZ + k];
        unsigned short h0 = f2bf(v0);
        int pa0 = a_addr(r, k);
        a_hi[pa0] = (short)h0; a_lo[pa0] = (short)f2bf(v0 - bf2f(h0));
        unsigned short h1 = f2bf(v1);
        int pa1 = a_addr(r + 8, k);
        a_hi[pa1] = (short)h1; a_lo[pa1] = (short)f2bf(v1 - bf2f(h1));
    }

    for (int s = 0; s < SEQ; ++s) {
        __syncthreads();              // A(s) complete (incl. sibling unpack)

        // prefetch x(s+1) early (hides under the MFMA phase)
        float xv0 = 0.f, xv1 = 0.f;
        if (s + 1 < SEQ) {
            int r = tid >> 5, k = tid & 31;
            xv0 = x[((size_t)(b0 + r)*SEQ + (s+1))*INSZ + k];
            xv1 = x[((size_t)(b0 + 8 + r)*SEQ + (s+1))*INSZ + k];
        }

        // ---- MFMA phase: A[16x288] (LDS) x register-resident W slice ----
        f32x4 acc[4];
        #pragma unroll
        for (int G = 0; G < 4; ++G) acc[G] = (f32x4){0.f,0.f,0.f,0.f};

        const int qs = (q ^ (l15 & 3)) << 3;
        #pragma unroll
        for (int c = 0; c < NKC; ++c) {
            int pk = l15*AS + c*32 + qs;
            bf16x8 ah = __builtin_bit_cast(bf16x8, *(const s16x8*)&a_hi[pk]);
            bf16x8 al = __builtin_bit_cast(bf16x8, *(const s16x8*)&a_lo[pk]);
            #pragma unroll
            for (int G = 0; G < 4; ++G) {
                acc[G] = __builtin_amdgcn_mfma_f32_16x16x32_bf16(ah, wh[c][G], acc[G], 0,0,0);
                acc[G] = __builtin_amdgcn_mfma_f32_16x16x32_bf16(ah, wl[c][G], acc[G], 0,0,0);
                acc[G] = __builtin_amdgcn_mfma_f32_16x16x32_bf16(al, wh[c][G], acc[G], 0,0,0);
            }
        }

        // ---- epilogue: activations, publish h slice (coherent), outputs ----
        unsigned int* hxw = hxg + (s & 1)*(16*HID);
        unsigned int hpk[4];
        #pragma unroll
        for (int i = 0; i < 4; ++i) {
            float f  = acc[0][i] + bia[0];
            float ii = acc[1][i] + bia[1];
            float o  = acc[2][i] + bia[2];
            float gg = acc[3][i] + bia[3];
            float cn = sigm(f)*cst[i] + sigm(ii)*tanh_f(gg);
            float hn = sigm(o)*tanh_f(cn);
            cst[i] = cn;
            unsigned short hi = f2bf(hn);
            unsigned short lo = f2bf(hn - bf2f(hi));
            unsigned int pk = ((unsigned int)hi << 16) | (unsigned int)lo;
            hpk[i] = pk;
            int row = q*4 + i;
            unsigned int* hp = hxw + row*HID + hcol;
            asm volatile("global_store_dword %0, %1, off sc0 sc1"
                         :: "v"(hp), "v"(pk) : "memory");
            size_t oi = ((size_t)(b0 + row)*SEQ + s)*HID + hcol;
            h_n[oi] = hn;
            c_n[oi] = cn;
        }

        // per-wave publish: drain own stores, then wave flag (no barrier needed first)
        asm volatile("s_waitcnt vmcnt(0)" ::: "memory");
        if ((tid & 63) == 0) {
            unsigned int fv = (unsigned int)(s + 1);
            asm volatile("global_store_dword %0, %1, off sc0 sc1"
                         :: "v"(flg + sl*4 + wv), "v"(fv) : "memory");
        }
        __syncthreads();              // all waves done reading A(s)

        if (s + 1 == SEQ && sl != 0) return;   // block-uniform; slice 0 does FC

        // ---- own h slice + x(s+1) straight into LDS A (no round trip) ----
        #pragma unroll
        for (int i = 0; i < 4; ++i) {
            int pa = a_addr(q*4 + i, INSZ + hcol);
            a_hi[pa] = (short)(hpk[i] >> 16);
            a_lo[pa] = (short)(hpk[i] & 0xffffu);
        }
        if (s + 1 < SEQ) {
            int r = tid >> 5, k = tid & 31;
            unsigned short h0 = f2bf(xv0);
            int pa0 = a_addr(r, k);
            a_hi[pa0] = (short)h0; a_lo[pa0] = (short)f2bf(xv0 - bf2f(h0));
            unsigned short h1 = f2bf(xv1);
            int pa1 = a_addr(r + 8, k);
            a_hi[pa1] = (short)h1; a_lo[pa1] = (short)f2bf(xv1 - bf2f(h1));
        }

        // ---- spin for all 16 wave-flags of the group (one 64B line) ----
        if (tid == 0) {
            unsigned int tgt = (unsigned int)(s + 1);
            while (1) {
                u32x4 f0, f1, f2, f3;
                asm volatile("global_load_dwordx4 %0, %4, off sc0 sc1\n\t"
                             "global_load_dwordx4 %1, %5, off sc0 sc1\n\t"
                             "global_load_dwordx4 %2, %6, off sc0 sc1\n\t"
                             "global_load_dwordx4 %3, %7, off sc0 sc1\n\t"
                             "s_waitcnt vmcnt(0)"
                             : "=v"(f0), "=v"(f1), "=v"(f2), "=v"(f3)
                             : "v"(flg), "v"(flg+4), "v"(flg+8), "v"(flg+12)
                             : "memory");
                bool ok = f0.x>=tgt && f0.y>=tgt && f0.z>=tgt && f0.w>=tgt
                       && f1.x>=tgt && f1.y>=tgt && f1.z>=tgt && f1.w>=tgt
                       && f2.x>=tgt && f2.y>=tgt && f2.z>=tgt && f2.w>=tgt
                       && f3.x>=tgt && f3.y>=tgt && f3.z>=tgt && f3.w>=tgt;
                if (ok) break;
            }
        }
        __syncthreads();

        // ---- sibling slices only: 12 KB coherent load, unpack into A ----
        const unsigned int* hxr = hxg + (s & 1)*(16*HID);
        const int rrow = tid >> 4, rc4 = (tid & 15) * 4;
        u32x4 hv[3];
        #pragma unroll
        for (int e = 0; e < 3; ++e) {
            int ss = (sl + 1 + e) & 3;
            const unsigned int* ap = hxr + rrow*HID + ss*64 + rc4;
            asm volatile("global_load_dwordx4 %0, %1, off sc0 sc1"
                         : "=v"(hv[e]) : "v"(ap) : "memory");
        }
        asm volatile("s_waitcnt vmcnt(0)" ::: "memory");
        __builtin_amdgcn_sched_barrier(0);
        #pragma unroll
        for (int e = 0; e < 3; ++e) {
            int ss = (sl + 1 + e) & 3;
            int pa = a_addr(rrow, INSZ + ss*64 + rc4);   // 4 shorts, 8B-aligned
            s16x4 hi4 = (s16x4){ (short)(hv[e].x >> 16), (short)(hv[e].y >> 16),
                                 (short)(hv[e].z >> 16), (short)(hv[e].w >> 16) };
            s16x4 lo4 = (s16x4){ (short)(hv[e].x & 0xffffu), (short)(hv[e].y & 0xffffu),
                                 (short)(hv[e].z & 0xffffu), (short)(hv[e].w & 0xffffu) };
            *(s16x4*)&a_hi[pa] = hi4;
            *(s16x4*)&a_lo[pa] = lo4;
        }
        // loop-top __syncthreads() makes unpack visible before next MFMA phase
    }

    // ---- final FC (slice-0 blocks): A h-region holds h(SEQ-1) hi/lo ----
    __syncthreads();
    {
        int r = tid >> 4, seg = tid & 15;
        float acc = 0.f;
        #pragma unroll
        for (int d = 0; d < 16; ++d) {
            int j = seg*16 + d;
            int pa = a_addr(r, INSZ + j);
            acc += (bf2f((unsigned short)a_hi[pa]) + bf2f((unsigned short)a_lo[pa])) * fc_w[j];
        }
        red[r*17 + seg] = acc;
    }
    __syncthreads();
    if (tid < 16) {
        float accv = fc_b[0];
        #pragma unroll
        for (int p = 0; p < 16; ++p) accv += red[tid*17 + p];
        out[b0 + tid] = accv;
    }
}

extern "C" void kernel_launch(void* const* d_in, const int* in_sizes, int n_in,
                              void* d_out, int out_size, void* d_ws, size_t ws_size,
                              hipStream_t stream) {
    const float* x    = (const float*)d_in[0];
    const float* w_ih = (const float*)d_in[1];
    const float* w_hh = (const float*)d_in[2];
    const float* bias = (const float*)d_in[3];
    const float* fc_w = (const float*)d_in[4];
    const float* fc_b = (const float*)d_in[5];

    float* out = (float*)d_out;
    float* h_n = out + BATCH;
    float* c_n = h_n + (size_t)BATCH*SEQ*HID;

    unsigned short* wsw   = (unsigned short*)d_ws;                       // 1.125 MB
    unsigned int*   flags = (unsigned int*)((char*)d_ws + FLAG_OFF);     // 1 KB
    unsigned int*   hx    = (unsigned int*)((char*)d_ws + HX_OFF);       // 512 KB

    swizzle_w<<<1152, 256, 0, stream>>>(w_ih, w_hh, wsw, flags);
    lstm_seq<<<NBLK, 256, 0, stream>>>(x, wsw, bias, fc_w, fc_b, out, h_n, c_n, flags, hx);
}

// Round 3
// 1323.170 us; speedup vs baseline: 5.4263x; 1.2318x over previous
//
#include <hip/hip_runtime.h>
#include <stdint.h>

#define BATCH 256
#define SEQ   365
#define HID   256
#define INSZ  32
#define NGATE 1024
#define KTOT  288            // INSZ + HID
#define NKC   9              // K chunks of 32
#define AS    296            // shorts per A row (XOR-swizzled 16B blocks)
#define WTOT  (KTOT*NGATE)   // 294912 elements per weight array

#define NSPLIT 4             // blocks per batch group (gate-column split)
#define NGRP   16            // batch groups of 16 rows
#define NBLK   (NGRP*NSPLIT) // 64 blocks
#define HSLICE 64            // hidden cols per block

#define NTAGW  (NGRP*2*16*HID)       // 131072 tagged pairs total
// workspace layout (bytes): wsw (1.125 MB) then tagged hx (1 MB)
#define HX_OFF (2*WTOT*2)

typedef __bf16 bf16x8 __attribute__((ext_vector_type(8)));
typedef short  s16x8  __attribute__((ext_vector_type(8)));
typedef short  s16x4  __attribute__((ext_vector_type(4)));
typedef float  f32x4  __attribute__((ext_vector_type(4)));
typedef unsigned int u32x4 __attribute__((ext_vector_type(4)));
typedef unsigned int u32x2 __attribute__((ext_vector_type(2)));

__device__ __forceinline__ unsigned short f2bf(float f) {
    unsigned u = __float_as_uint(f);
    u += 0x7FFFu + ((u >> 16) & 1u);          // round-to-nearest-even
    return (unsigned short)(u >> 16);
}
__device__ __forceinline__ float bf2f(unsigned short h) {
    return __uint_as_float(((unsigned)h) << 16);
}
__device__ __forceinline__ float sigm(float x) { return 1.f / (1.f + __expf(-x)); }
__device__ __forceinline__ float tanh_f(float x) {
    float e = __expf(-2.f * fabsf(x));
    float r = (1.f - e) / (1.f + e);
    return copysignf(r, x);
}

// One-time: W^T (w_ih stacked over w_hh) -> bf16 hi/lo in MFMA-B-fragment order.
// Also zeroes all hx tag words (re-runs every launch -> graph-replay safe; plain
// stores + kernel-boundary L2 writeback = coherent, same mechanism as old flags).
__global__ void swizzle_w(const float* __restrict__ w_ih,
                          const float* __restrict__ w_hh,
                          unsigned short* __restrict__ wsw,
                          unsigned int* __restrict__ hx)
{
    int idx = blockIdx.x*256 + threadIdx.x;      // idx = k*1024 + n
    if (idx < NTAGW) hx[2*idx + 1] = 0u;         // clear tag word of pair idx
    int k = idx >> 10, n = idx & 1023;
    float v = (k < INSZ) ? w_ih[k*NGATE + n] : w_hh[(k-INSZ)*NGATE + n];
    unsigned short hi = f2bf(v);
    unsigned short lo = f2bf(v - bf2f(hi));
    int t = n >> 4, l15 = n & 15, c = k >> 5, q = (k >> 3) & 3, j = k & 7;
    int off = ((t*NKC + c)*64 + q*16 + l15)*8 + j;
    wsw[off]        = hi;
    wsw[WTOT + off] = lo;
}

// Physical LDS address for A element (row r, logical k): 16B blocks XOR-swizzled by r&3.
__device__ __forceinline__ int a_addr(int r, int k) {
    return r*AS + ((((k >> 3) ^ (r & 3))) << 3) + (k & 7);
}

__global__ __launch_bounds__(256, 1) void lstm_seq(
    const float* __restrict__ x,      // [B][SEQ][INSZ]
    const unsigned short* __restrict__ wsw,
    const float* __restrict__ bias,   // [NGATE]
    const float* __restrict__ fc_w,   // [HID]
    const float* __restrict__ fc_b,   // [1]
    float* __restrict__ out,          // [B]
    float* __restrict__ h_n,          // [B][SEQ][HID]
    float* __restrict__ c_n,          // [B][SEQ][HID]
    unsigned int* __restrict__ hx)    // [NGRP][2][16][HID] x (value, tag) u32 pairs
{
    __shared__ short a_hi[16*AS];     // A = [x_t | h] hi, XOR-swizzled blocks
    __shared__ short a_lo[16*AS];
    __shared__ float red[16*17];      // FC reduction

    const int tid  = threadIdx.x;
    const int gq   = blockIdx.x >> 2;       // batch group
    const int sl   = blockIdx.x & 3;        // gate-column slice
    const int b0   = gq * 16;
    const int wv   = tid >> 6, lane = tid & 63;
    const int l15  = lane & 15, q = lane >> 4;
    const int hcol = sl*HSLICE + wv*16 + l15;   // this thread's hidden column

    unsigned int* const hxg = hx + (size_t)gq * 2 * (16*HID) * 2;

    // ---- one-time: this block's W slice -> registers (72 frag pairs, 288 VGPRs) ----
    // frag (c,G): wsw[((tile*NKC + c)*64 + lane)*8], tile = G*16 + sl*4 + wv
    const unsigned short* wbase = wsw + ((size_t)((sl*4 + wv)*NKC)*64 + lane)*8;
    u32x4 wh[NKC][4], wl[NKC][4];
    #pragma unroll
    for (int c = 0; c < NKC; ++c)
        #pragma unroll
        for (int G = 0; G < 4; ++G) {
            const unsigned short* wp = wbase + (size_t)(G*16*NKC + c)*512;
            wh[c][G] = *(const u32x4*)wp;
            wl[c][G] = *(const u32x4*)(wp + WTOT);
        }
    // Pin W fragments in VGPRs: opaque redefinition stops the compiler from
    // sinking/rematerializing these loads inside the s-loop (R2: VGPR=196 < 288
    // showed half the slice was being re-streamed from L2 every step).
    #pragma unroll
    for (int c = 0; c < NKC; ++c)
        #pragma unroll
        for (int G = 0; G < 4; ++G)
            asm volatile("" : "+v"(wh[c][G]), "+v"(wl[c][G]));

    float bia[4];
    #pragma unroll
    for (int G = 0; G < 4; ++G) bia[G] = bias[G*HID + hcol];

    float cst[4];                     // c state: row = q*4+i, col = hcol
    #pragma unroll
    for (int i = 0; i < 4; ++i) cst[i] = 0.f;

    // ---- initial staging: zero all of A, then x(s=0) ----
    for (int i = tid; i < 16*AS; i += 256) { a_hi[i] = 0; a_lo[i] = 0; }
    __syncthreads();
    {
        int r = tid >> 5, k = tid & 31;       // rows 0..7 and 8..15
        float v0 = x[((size_t)(b0 + r)*SEQ + 0)*INSZ + k];
        float v1 = x[((size_t)(b0 + 8 + r)*SEQ + 0)*INSZ + k];
        unsigned short h0 = f2bf(v0);
        int pa0 = a_addr(r, k);
        a_hi[pa0] = (short)h0; a_lo[pa0] = (short)f2bf(v0 - bf2f(h0));
        unsigned short h1 = f2bf(v1);
        int pa1 = a_addr(r + 8, k);
        a_hi[pa1] = (short)h1; a_lo[pa1] = (short)f2bf(v1 - bf2f(h1));
    }

    for (int s = 0; s < SEQ; ++s) {
        __syncthreads();              // A(s) complete (incl. sibling unpack)

        // prefetch x(s+1) early (hides under the MFMA phase)
        float xv0 = 0.f, xv1 = 0.f;
        if (s + 1 < SEQ) {
            int r = tid >> 5, k = tid & 31;
            xv0 = x[((size_t)(b0 + r)*SEQ + (s+1))*INSZ + k];
            xv1 = x[((size_t)(b0 + 8 + r)*SEQ + (s+1))*INSZ + k];
        }

        // ---- MFMA phase: A[16x288] (LDS) x register-resident W slice ----
        f32x4 acc[4];
        #pragma unroll
        for (int G = 0; G < 4; ++G) acc[G] = (f32x4){0.f,0.f,0.f,0.f};

        const int qs = (q ^ (l15 & 3)) << 3;
        #pragma unroll
        for (int c = 0; c < NKC; ++c) {
            int pk = l15*AS + c*32 + qs;
            bf16x8 ah = __builtin_bit_cast(bf16x8, *(const s16x8*)&a_hi[pk]);
            bf16x8 al = __builtin_bit_cast(bf16x8, *(const s16x8*)&a_lo[pk]);
            #pragma unroll
            for (int G = 0; G < 4; ++G) {
                acc[G] = __builtin_amdgcn_mfma_f32_16x16x32_bf16(ah, __builtin_bit_cast(bf16x8, wh[c][G]), acc[G], 0,0,0);
                acc[G] = __builtin_amdgcn_mfma_f32_16x16x32_bf16(ah, __builtin_bit_cast(bf16x8, wl[c][G]), acc[G], 0,0,0);
                acc[G] = __builtin_amdgcn_mfma_f32_16x16x32_bf16(al, __builtin_bit_cast(bf16x8, wh[c][G]), acc[G], 0,0,0);
            }
        }

        // ---- epilogue: activations; publish tagged h pairs FIRST, then streams ----
        const unsigned int tag = (unsigned int)(s + 1);
        unsigned int* hxw = hxg + (s & 1)*(16*HID*2);
        unsigned int hpk[4];
        float hnv[4], cnv[4];
        #pragma unroll
        for (int i = 0; i < 4; ++i) {
            float f  = acc[0][i] + bia[0];
            float ii = acc[1][i] + bia[1];
            float o  = acc[2][i] + bia[2];
            float gg = acc[3][i] + bia[3];
            float cn = sigm(f)*cst[i] + sigm(ii)*tanh_f(gg);
            float hn = sigm(o)*tanh_f(cn);
            cst[i] = cn; cnv[i] = cn; hnv[i] = hn;
            unsigned short hi = f2bf(hn);
            unsigned short lo = f2bf(hn - bf2f(hi));
            hpk[i] = ((unsigned int)hi << 16) | (unsigned int)lo;
        }
        #pragma unroll
        for (int i = 0; i < 4; ++i) {     // tagged publish: value+tag in ONE 8B store
            u32x2 pkt = (u32x2){ hpk[i], tag };
            unsigned int* hp = hxw + ((q*4 + i)*HID + hcol)*2;
            asm volatile("global_store_dwordx2 %0, %1, off sc0 sc1"
                         :: "v"(hp), "v"(pkt) : "memory");
        }
        #pragma unroll
        for (int i = 0; i < 4; ++i) {     // fire-and-forget output streams
            size_t oi = ((size_t)(b0 + q*4 + i)*SEQ + s)*HID + hcol;
            h_n[oi] = hnv[i];
            c_n[oi] = cnv[i];
        }

        __syncthreads();              // all waves done reading A(s)

        if (s + 1 == SEQ && sl != 0) return;   // block-uniform; slice 0 does FC

        // ---- own h slice + x(s+1) straight into LDS A (no round trip) ----
        #pragma unroll
        for (int i = 0; i < 4; ++i) {
            int pa = a_addr(q*4 + i, INSZ + hcol);
            a_hi[pa] = (short)(hpk[i] >> 16);
            a_lo[pa] = (short)(hpk[i] & 0xffffu);
        }
        if (s + 1 < SEQ) {
            int r = tid >> 5, k = tid & 31;
            unsigned short h0 = f2bf(xv0);
            int pa0 = a_addr(r, k);
            a_hi[pa0] = (short)h0; a_lo[pa0] = (short)f2bf(xv0 - bf2f(h0));
            unsigned short h1 = f2bf(xv1);
            int pa1 = a_addr(r + 8, k);
            a_hi[pa1] = (short)h1; a_lo[pa1] = (short)f2bf(xv1 - bf2f(h1));
        }

        // ---- decentralized poll: each thread polls the 12 tagged pairs it unpacks ----
        const unsigned int* hxr = hxg + (s & 1)*(16*HID*2);
        const int rrow = tid >> 4, rc4 = (tid & 15) * 4;
        const int ss0 = (sl + 1) & 3, ss1 = (sl + 2) & 3, ss2 = (sl + 3) & 3;
        const unsigned int* ap0 = hxr + (rrow*HID + ss0*64 + rc4)*2;
        const unsigned int* ap1 = hxr + (rrow*HID + ss1*64 + rc4)*2;
        const unsigned int* ap2 = hxr + (rrow*HID + ss2*64 + rc4)*2;
        u32x4 v00, v01, v10, v11, v20, v21;
        while (1) {
            asm volatile(
                "global_load_dwordx4 %0, %6, off sc0 sc1\n\t"
                "global_load_dwordx4 %1, %6, off offset:16 sc0 sc1\n\t"
                "global_load_dwordx4 %2, %7, off sc0 sc1\n\t"
                "global_load_dwordx4 %3, %7, off offset:16 sc0 sc1\n\t"
                "global_load_dwordx4 %4, %8, off sc0 sc1\n\t"
                "global_load_dwordx4 %5, %8, off offset:16 sc0 sc1\n\t"
                "s_waitcnt vmcnt(0)"
                : "=&v"(v00), "=&v"(v01), "=&v"(v10), "=&v"(v11), "=&v"(v20), "=&v"(v21)
                : "v"(ap0), "v"(ap1), "v"(ap2)
                : "memory");
            if (v00.y >= tag && v00.w >= tag && v01.y >= tag && v01.w >= tag &&
                v10.y >= tag && v10.w >= tag && v11.y >= tag && v11.w >= tag &&
                v20.y >= tag && v20.w >= tag && v21.y >= tag && v21.w >= tag) break;
        }
        __builtin_amdgcn_sched_barrier(0);

        // values are already in registers: unpack straight into A
        {
            int pa = a_addr(rrow, INSZ + ss0*64 + rc4);
            *(s16x4*)&a_hi[pa] = (s16x4){ (short)(v00.x >> 16), (short)(v00.z >> 16),
                                          (short)(v01.x >> 16), (short)(v01.z >> 16) };
            *(s16x4*)&a_lo[pa] = (s16x4){ (short)(v00.x & 0xffffu), (short)(v00.z & 0xffffu),
                                          (short)(v01.x & 0xffffu), (short)(v01.z & 0xffffu) };
        }
        {
            int pa = a_addr(rrow, INSZ + ss1*64 + rc4);
            *(s16x4*)&a_hi[pa] = (s16x4){ (short)(v10.x >> 16), (short)(v10.z >> 16),
                                          (short)(v11.x >> 16), (short)(v11.z >> 16) };
            *(s16x4*)&a_lo[pa] = (s16x4){ (short)(v10.x & 0xffffu), (short)(v10.z & 0xffffu),
                                          (short)(v11.x & 0xffffu), (short)(v11.z & 0xffffu) };
        }
        {
            int pa = a_addr(rrow, INSZ + ss2*64 + rc4);
            *(s16x4*)&a_hi[pa] = (s16x4){ (short)(v20.x >> 16), (short)(v20.z >> 16),
                                          (short)(v21.x >> 16), (short)(v21.z >> 16) };
            *(s16x4*)&a_lo[pa] = (s16x4){ (short)(v20.x & 0xffffu), (short)(v20.z & 0xffffu),
                                          (short)(v21.x & 0xffffu), (short)(v21.z & 0xffffu) };
        }
        // loop-top __syncthreads() makes unpack visible before next MFMA phase
    }

    // ---- final FC (slice-0 blocks): A h-region holds h(SEQ-1) hi/lo ----
    __syncthreads();
    {
        int r = tid >> 4, seg = tid & 15;
        float acc = 0.f;
        #pragma unroll
        for (int d = 0; d < 16; ++d) {
            int j = seg*16 + d;
            int pa = a_addr(r, INSZ + j);
            acc += (bf2f((unsigned short)a_hi[pa]) + bf2f((unsigned short)a_lo[pa])) * fc_w[j];
        }
        red[r*17 + seg] = acc;
    }
    __syncthreads();
    if (tid < 16) {
        float accv = fc_b[0];
        #pragma unroll
        for (int p = 0; p < 16; ++p) accv += red[tid*17 + p];
        out[b0 + tid] = accv;
    }
}

extern "C" void kernel_launch(void* const* d_in, const int* in_sizes, int n_in,
                              void* d_out, int out_size, void* d_ws, size_t ws_size,
                              hipStream_t stream) {
    const float* x    = (const float*)d_in[0];
    const float* w_ih = (const float*)d_in[1];
    const float* w_hh = (const float*)d_in[2];
    const float* bias = (const float*)d_in[3];
    const float* fc_w = (const float*)d_in[4];
    const float* fc_b = (const float*)d_in[5];

    float* out = (float*)d_out;
    float* h_n = out + BATCH;
    float* c_n = h_n + (size_t)BATCH*SEQ*HID;

    unsigned short* wsw = (unsigned short*)d_ws;                    // 1.125 MB
    unsigned int*   hx  = (unsigned int*)((char*)d_ws + HX_OFF);    // 1 MB tagged pairs

    swizzle_w<<<1152, 256, 0, stream>>>(w_ih, w_hh, wsw, hx);
    lstm_seq<<<NBLK, 256, 0, stream>>>(x, wsw, bias, fc_w, fc_b, out, h_n, c_n, hx);
}